// Round 2
// baseline (716.824 us; speedup 1.0000x reference)
//
#include <hip/hip_runtime.h>

constexpr int F_IN = 512;
constexpr int HID  = 16;
constexpr int NCLS = 40;
constexpr int NPAD = 102400;   // N rounded up to 1024

// deg[n]=1 (self-loop), cnt[n]=0 over padded range
__global__ void k_init(float* __restrict__ deg, int* __restrict__ cnt, int N, int Npad) {
  int n = blockIdx.x * blockDim.x + threadIdx.x;
  if (n < Npad) {
    cnt[n] = 0;
    deg[n] = (n < N) ? 1.0f : 0.0f;
  }
}

// per-edge: accumulate weighted degree + in-degree count
__global__ void k_degcnt(const int* __restrict__ dst, const float* __restrict__ ew,
                         float* __restrict__ deg, int* __restrict__ cnt, int E) {
  int e = blockIdx.x * blockDim.x + threadIdx.x;
  if (e < E) {
    int d = dst[e];
    atomicAdd(&deg[d], ew[e]);
    atomicAdd(&cnt[d], 1);
  }
}

__global__ void k_dis(float* __restrict__ deg, int N) {
  int n = blockIdx.x * blockDim.x + threadIdx.x;
  if (n < N) {
    float d = deg[n];
    deg[n] = (d > 0.0f) ? rsqrtf(d) : 0.0f;
  }
}

// ---- scan: cnt (Npad, zero-padded) -> exclusive prefix row_start ----
__global__ void k_scan1(const int* __restrict__ cnt, int* __restrict__ bsum) {
  __shared__ int sd[256];
  int t = threadIdx.x;
  const int4 v = reinterpret_cast<const int4*>(cnt)[blockIdx.x * 256 + t];
  int s = v.x + v.y + v.z + v.w;
  sd[t] = s; __syncthreads();
  for (int off = 128; off > 0; off >>= 1) {
    if (t < off) sd[t] += sd[t + off];
    __syncthreads();
  }
  if (t == 0) bsum[blockIdx.x] = sd[0];
}

__global__ void k_scan2(int* __restrict__ bsum, int nb, int* __restrict__ row_start,
                        int N, int E) {
  if (threadIdx.x == 0) {
    int acc = 0;
    for (int i = 0; i < nb; ++i) { int v = bsum[i]; bsum[i] = acc; acc += v; }
    row_start[N] = E;
  }
}

__global__ void k_scan3(const int* __restrict__ cnt, const int* __restrict__ bsum,
                        int* __restrict__ row_start, int* __restrict__ cursor, int N) {
  __shared__ int sd[256];
  int t = threadIdx.x;
  int base = blockIdx.x * 1024 + t * 4;
  const int4 v = reinterpret_cast<const int4*>(cnt)[blockIdx.x * 256 + t];
  int tsum = v.x + v.y + v.z + v.w;
  sd[t] = tsum; __syncthreads();
  // Hillis-Steele inclusive scan
  for (int off = 1; off < 256; off <<= 1) {
    int add = (t >= off) ? sd[t - off] : 0;
    __syncthreads();
    sd[t] += add;
    __syncthreads();
  }
  int pre = bsum[blockIdx.x] + sd[t] - tsum;  // exclusive
  int p0 = pre, p1 = pre + v.x, p2 = p1 + v.y, p3 = p2 + v.z;
  if (base + 0 < N) { row_start[base + 0] = p0; cursor[base + 0] = p0; }
  if (base + 1 < N) { row_start[base + 1] = p1; cursor[base + 1] = p1; }
  if (base + 2 < N) { row_start[base + 2] = p2; cursor[base + 2] = p2; }
  if (base + 3 < N) { row_start[base + 3] = p3; cursor[base + 3] = p3; }
}

// scatter edges into CSR order; fold in the normalization weight
__global__ void k_scatter(const int* __restrict__ src, const int* __restrict__ dst,
                          const float* __restrict__ ew, const float* __restrict__ dis,
                          int* __restrict__ cursor, uint2* __restrict__ edges, int E) {
  int e = blockIdx.x * blockDim.x + threadIdx.x;
  if (e >= E) return;
  int s = src[e], d = dst[e];
  float nrm = dis[s] * ew[e] * dis[d];
  int pos = atomicAdd(&cursor[d], 1);
  edges[pos] = make_uint2((unsigned)s, __float_as_uint(nrm));
}

// h1 = x @ W1 : thread-per-row
__global__ void k_gemm1(const float* __restrict__ x, const float* __restrict__ W1,
                        float* __restrict__ h1, int N) {
  int n = blockIdx.x * blockDim.x + threadIdx.x;
  if (n >= N) return;
  const float* xr = x + (size_t)n * F_IN;
  float acc[HID];
#pragma unroll
  for (int j = 0; j < HID; ++j) acc[j] = 0.0f;
  for (int k = 0; k < F_IN; k += 16) {
    float4 a0 = *reinterpret_cast<const float4*>(xr + k);
    float4 a1 = *reinterpret_cast<const float4*>(xr + k + 4);
    float4 a2 = *reinterpret_cast<const float4*>(xr + k + 8);
    float4 a3 = *reinterpret_cast<const float4*>(xr + k + 12);
    float xv[16] = {a0.x, a0.y, a0.z, a0.w, a1.x, a1.y, a1.z, a1.w,
                    a2.x, a2.y, a2.z, a2.w, a3.x, a3.y, a3.z, a3.w};
#pragma unroll
    for (int kk = 0; kk < 16; ++kk) {
      float xx = xv[kk];
      const float* wr = W1 + (size_t)(k + kk) * HID;
#pragma unroll
      for (int j = 0; j < HID; ++j) acc[j] = fmaf(xx, wr[j], acc[j]);
    }
  }
  float* hr = h1 + (size_t)n * HID;
#pragma unroll
  for (int j = 0; j < HID; ++j) hr[j] = acc[j];
}

// CSR gather-aggregate: one wave per dst node; lanes = 16 features x 4 edge groups.
// Epilogue fuses self-loop + optional bias + optional relu.
template <bool RELU>
__global__ void k_agg_csr(const uint2* __restrict__ edges, const int* __restrict__ rs,
                          const float* __restrict__ h, const float* __restrict__ dis,
                          const float* __restrict__ bias, float* __restrict__ out, int N) {
  int wid = blockIdx.x * 4 + (threadIdx.x >> 6);
  if (wid >= N) return;
  int lane = threadIdx.x & 63;
  int j = lane & 15, g = lane >> 4;
  int beg = rs[wid], end = rs[wid + 1];
  float acc = 0.0f;
  for (int e = beg + g; e < end; e += 4) {
    uint2 p = edges[e];
    acc = fmaf(h[((size_t)p.x << 4) + j], __uint_as_float(p.y), acc);
  }
  acc += __shfl_xor(acc, 16);
  acc += __shfl_xor(acc, 32);
  if (lane < 16) {
    float di = dis[wid];
    float v = acc + h[((size_t)wid << 4) + j] * di * di;
    if (bias) v += bias[j];
    if (RELU) v = fmaxf(v, 0.0f);
    out[((size_t)wid << 4) + j] = v;
  }
}

// out = log_softmax(g @ W2 + b2)
__global__ void k_out(const float* __restrict__ g, const float* __restrict__ W2,
                      const float* __restrict__ b2, float* __restrict__ out, int N) {
  int n = blockIdx.x * blockDim.x + threadIdx.x;
  if (n >= N) return;
  float gv[HID];
#pragma unroll
  for (int j = 0; j < HID; ++j) gv[j] = g[(size_t)n * HID + j];
  float o[NCLS];
#pragma unroll
  for (int c = 0; c < NCLS; ++c) o[c] = b2[c];
#pragma unroll
  for (int j = 0; j < HID; ++j) {
    float gj = gv[j];
    const float* wr = W2 + (size_t)j * NCLS;
#pragma unroll
    for (int c = 0; c < NCLS; ++c) o[c] = fmaf(gj, wr[c], o[c]);
  }
  float m = o[0];
#pragma unroll
  for (int c = 1; c < NCLS; ++c) m = fmaxf(m, o[c]);
  float ssum = 0.0f;
#pragma unroll
  for (int c = 0; c < NCLS; ++c) ssum += expf(o[c] - m);
  float lse = m + logf(ssum);
  float* orow = out + (size_t)n * NCLS;
#pragma unroll
  for (int c = 0; c < NCLS; ++c) orow[c] = o[c] - lse;
}

extern "C" void kernel_launch(void* const* d_in, const int* in_sizes, int n_in,
                              void* d_out, int out_size, void* d_ws, size_t ws_size,
                              hipStream_t stream) {
  const float* x  = (const float*)d_in[0];
  const int*   ei = (const int*)d_in[1];
  const float* ew = (const float*)d_in[2];
  const float* W1 = (const float*)d_in[3];
  const float* b1 = (const float*)d_in[4];
  const float* W2 = (const float*)d_in[5];
  const float* b2 = (const float*)d_in[6];
  float* out = (float*)d_out;

  const int N = in_sizes[0] / F_IN;   // 100000
  const int E = in_sizes[2];          // 3200000
  const int* src = ei;
  const int* dst = ei + E;

  // Workspace layout (4B units):
  // dis[NPAD] | cnt[NPAD] | row_start[NPAD] | bsum[256] | h1[N*16] | h2[N*16] | edges[2*E]
  // cursor aliases cnt (scan3 reads cnt before writing cursor; disjoint per block is fine
  // because each block reads its cnt chunk into registers before any cursor write).
  float* ws  = (float*)d_ws;
  float* dis = ws;
  int* cnt   = (int*)(ws + NPAD);
  int* rs    = (int*)(ws + 2 * NPAD);
  int* bsum  = (int*)(ws + 3 * NPAD);
  float* h1  = ws + 3 * NPAD + 256;
  float* h2  = h1 + (size_t)N * HID;
  uint2* edges = (uint2*)(h2 + (size_t)N * HID);
  int* cursor = cnt;
  float* g = h1;  // reuse: h1 dead after agg1

  const int B = 256;
  const int gNp = (NPAD + B - 1) / B;
  const int gN  = (N + B - 1) / B;
  const int gE  = (E + B - 1) / B;
  const int nb  = NPAD / 1024;  // 100 scan blocks

  k_init<<<gNp, B, 0, stream>>>(dis, cnt, N, NPAD);
  k_degcnt<<<gE, B, 0, stream>>>(dst, ew, dis, cnt, E);
  k_dis<<<gN, B, 0, stream>>>(dis, N);
  k_scan1<<<nb, B, 0, stream>>>(cnt, bsum);
  k_scan2<<<1, 64, 0, stream>>>(bsum, nb, rs, N, E);
  k_scan3<<<nb, B, 0, stream>>>(cnt, bsum, rs, cursor, N);
  k_scatter<<<gE, B, 0, stream>>>(src, dst, ew, dis, cursor, edges, E);
  k_gemm1<<<gN, B, 0, stream>>>(x, W1, h1, N);
  k_agg_csr<true><<<(N + 3) / 4, B, 0, stream>>>(edges, rs, h1, dis, b1, h2, N);
  k_agg_csr<false><<<(N + 3) / 4, B, 0, stream>>>(edges, rs, h2, dis, nullptr, g, N);
  k_out<<<gN, B, 0, stream>>>(g, W2, b2, out, N);
}